// Round 2
// baseline (472.465 us; speedup 1.0000x reference)
//
#include <hip/hip_runtime.h>
#include <math.h>

#define B_DIM 8
#define T_DIM 2048
#define D_DIM 1024
#define H_DIM 64
#define SCALE 0.125f
#define NT (T_DIM / 64)          // 32 q/k tiles of 64
#define NPAIR (NT * (NT + 1) / 2) // 528 causal tile pairs

// triangular decode: p = qt*(qt+1)/2 + kt, kt <= qt
__device__ __forceinline__ void decode_pair(int p, int& qt, int& kt) {
    float f = sqrtf(8.0f * (float)p + 1.0f);
    int q = (int)((f - 1.0f) * 0.5f);
    while ((q + 1) * (q + 2) / 2 <= p) q++;
    while (q * (q + 1) / 2 > p) q--;
    qt = q;
    kt = p - q * (q + 1) / 2;
}

__device__ __forceinline__ void atomic_add_f32(float* addr, float v) {
    unsafeAtomicAdd(addr, v);  // HW global_atomic_add_f32 (denormals irrelevant here)
}

// ---------------------------------------------------------------------------
// zero out (4 MB) + Zbuf (64 KB)
// ---------------------------------------------------------------------------
__global__ __launch_bounds__(256) void zero_kernel(float4* out4, float4* z4) {
    int idx = blockIdx.x * 256 + threadIdx.x;
    float4 z = make_float4(0.f, 0.f, 0.f, 0.f);
    if (idx < 262144) {
        out4[idx] = z;
    } else {
        int j = idx - 262144;
        if (j < 4096) z4[j] = z;
    }
}

// ---------------------------------------------------------------------------
// Kernel A: projections. grid (16384/128, 3), block 256.
// 128 rows x 64 cols per block; thread: (4+4) rows x 4 cols.
// xs stored transposed [kk][row] -> float4 reads, no 16-way conflicts.
// ---------------------------------------------------------------------------
__global__ __launch_bounds__(256) void proj_kernel(
    const float* __restrict__ x,
    const float* __restrict__ Wq, const float* __restrict__ Wk,
    const float* __restrict__ Wv,
    float* __restrict__ qb, float* __restrict__ kb, float* __restrict__ vb)
{
    __shared__ float xs_t[64][132];  // [kk][row], pitch 132 (16B-aligned float4 cols)
    __shared__ float ws[64][68];     // [kk][col]

    const int tid = threadIdx.x;
    const int i = tid >> 4;          // 0..15
    const int j = tid & 15;          // 0..15
    const int row0 = blockIdx.x * 128;

    const float* W;
    float* dst;
    if (blockIdx.y == 0)      { W = Wq; dst = qb; }
    else if (blockIdx.y == 1) { W = Wk; dst = kb; }
    else                      { W = Wv; dst = vb; }

    float acc[8][4];
#pragma unroll
    for (int u = 0; u < 8; u++)
#pragma unroll
        for (int w = 0; w < 4; w++) acc[u][w] = 0.f;

    for (int k0 = 0; k0 < D_DIM; k0 += 64) {
        __syncthreads();
        // stage x tile transposed: 128 rows x 64 k
#pragma unroll
        for (int t = 0; t < 8; t++) {
            int fi = tid + t * 256;          // 0..2047
            int r = fi >> 4;                 // 0..127
            int c4 = (fi & 15) << 2;         // 0..60
            float4 v = *(const float4*)&x[(size_t)(row0 + r) * D_DIM + k0 + c4];
            xs_t[c4 + 0][r] = v.x; xs_t[c4 + 1][r] = v.y;
            xs_t[c4 + 2][r] = v.z; xs_t[c4 + 3][r] = v.w;
        }
        // stage W tile: 64 k x 64 cols
#pragma unroll
        for (int t = 0; t < 4; t++) {
            int fi = tid + t * 256;          // 0..1023
            int kk = fi >> 4;
            int c = (fi & 15) << 2;
            *(float4*)&ws[kk][c] = *(const float4*)&W[(size_t)(k0 + kk) * H_DIM + c];
        }
        __syncthreads();
#pragma unroll 4
        for (int kk = 0; kk < 64; kk++) {
            float4 a0 = *(const float4*)&xs_t[kk][i * 4];
            float4 a1 = *(const float4*)&xs_t[kk][64 + i * 4];
            float4 wv = *(const float4*)&ws[kk][j * 4];
            float aa[8] = {a0.x, a0.y, a0.z, a0.w, a1.x, a1.y, a1.z, a1.w};
#pragma unroll
            for (int u = 0; u < 8; u++) {
                acc[u][0] += aa[u] * wv.x;
                acc[u][1] += aa[u] * wv.y;
                acc[u][2] += aa[u] * wv.z;
                acc[u][3] += aa[u] * wv.w;
            }
        }
    }
#pragma unroll
    for (int u = 0; u < 8; u++) {
        int r = (u < 4) ? (i * 4 + u) : (64 + i * 4 + (u - 4));
        float4 o;
        o.x = acc[u][0]; o.y = acc[u][1]; o.z = acc[u][2]; o.w = acc[u][3];
        *(float4*)&dst[(size_t)(row0 + r) * H_DIM + j * 4] = o;
    }
}

// ---------------------------------------------------------------------------
// Kernel B: column denominators Z[k] = sum_{q>=k} exp(s*scale), no max needed
// (s*scale ~ N(0,1); exp stays < ~500, Z < ~4000 -> fp32 safe).
// grid (528, B): one block per causal (qt,kt) tile pair -> uniform load.
// ---------------------------------------------------------------------------
__global__ __launch_bounds__(256) void stats_kernel(
    const float* __restrict__ qb, const float* __restrict__ kb,
    float* __restrict__ Zbuf)
{
    __shared__ float Kst[64][68];   // [h][kcol]
    __shared__ float Qst[64][68];   // [h][qrow]
    __shared__ float red_z[16][64];

    const int tid = threadIdx.x;
    const int i = tid >> 4;
    const int j = tid & 15;
    const int b = blockIdx.y;
    int qt, kt;
    decode_pair(blockIdx.x, qt, kt);

    const float* Qb = qb + (size_t)b * T_DIM * H_DIM;
    const float* Kb = kb + (size_t)b * T_DIM * H_DIM;

#pragma unroll
    for (int t = 0; t < 4; t++) {
        int fi = tid + t * 256;
        int c = fi >> 4;
        int h = (fi & 15) << 2;
        float4 v = *(const float4*)&Kb[(size_t)(kt * 64 + c) * H_DIM + h];
        Kst[h + 0][c] = v.x; Kst[h + 1][c] = v.y;
        Kst[h + 2][c] = v.z; Kst[h + 3][c] = v.w;
        float4 q = *(const float4*)&Qb[(size_t)(qt * 64 + c) * H_DIM + h];
        Qst[h + 0][c] = q.x; Qst[h + 1][c] = q.y;
        Qst[h + 2][c] = q.z; Qst[h + 3][c] = q.w;
    }
    __syncthreads();

    float s[4][4];
#pragma unroll
    for (int u = 0; u < 4; u++)
#pragma unroll
        for (int w = 0; w < 4; w++) s[u][w] = 0.f;

#pragma unroll 4
    for (int h = 0; h < 64; h++) {
        float4 qv = *(const float4*)&Qst[h][i * 4];
        float4 kv = *(const float4*)&Kst[h][j * 4];
        float qa[4] = {qv.x, qv.y, qv.z, qv.w};
        float ka[4] = {kv.x, kv.y, kv.z, kv.w};
#pragma unroll
        for (int u = 0; u < 4; u++)
#pragma unroll
            for (int w = 0; w < 4; w++) s[u][w] += qa[u] * ka[w];
    }

    const bool diag = (qt == kt);
    float colz[4];
#pragma unroll
    for (int w = 0; w < 4; w++) {
        float z = 0.f;
#pragma unroll
        for (int u = 0; u < 4; u++) {
            bool ok = !diag || (i * 4 + u >= j * 4 + w);
            z += ok ? __expf(s[u][w] * SCALE) : 0.f;
        }
        colz[w] = z;
    }
#pragma unroll
    for (int w = 0; w < 4; w++) red_z[i][j * 4 + w] = colz[w];
    __syncthreads();
    if (tid < 64) {
        float z = 0.f;
#pragma unroll
        for (int r = 0; r < 16; r++) z += red_z[r][tid];
        atomic_add_f32(&Zbuf[(size_t)b * T_DIM + kt * 64 + tid], z);
    }
}

// ---------------------------------------------------------------------------
// Kernel C: output. grid (528, B): one block per causal tile pair.
// S = Q K^T; P = exp(S*scale)/Z (masked); atomicAdd P V into out.
// LDS: Kst | Vs | QP (Q transposed, then reused to hold P).
// ---------------------------------------------------------------------------
__global__ __launch_bounds__(256) void out_kernel(
    const float* __restrict__ qb, const float* __restrict__ kb,
    const float* __restrict__ vb, const float* __restrict__ Zbuf,
    float* __restrict__ out)
{
    __shared__ float pool[3 * 64 * 68];
    float* Kst = pool;                 // [h][kcol]  pitch 68
    float* Vs  = pool + 64 * 68;       // [kcol][h]  pitch 68
    float* QP  = pool + 2 * 64 * 68;   // Qst [h][qrow] then Ps [qrow][kcol]

    const int tid = threadIdx.x;
    const int i = tid >> 4;
    const int j = tid & 15;
    const int b = blockIdx.y;
    int qt, kt;
    decode_pair(blockIdx.x, qt, kt);

    const float* Qb = qb + (size_t)b * T_DIM * H_DIM;
    const float* Kb = kb + (size_t)b * T_DIM * H_DIM;
    const float* Vb = vb + (size_t)b * T_DIM * H_DIM;

#pragma unroll
    for (int t = 0; t < 4; t++) {
        int fi = tid + t * 256;
        int c = fi >> 4;
        int h = (fi & 15) << 2;
        float4 v = *(const float4*)&Kb[(size_t)(kt * 64 + c) * H_DIM + h];
        Kst[(h + 0) * 68 + c] = v.x; Kst[(h + 1) * 68 + c] = v.y;
        Kst[(h + 2) * 68 + c] = v.z; Kst[(h + 3) * 68 + c] = v.w;
        float4 q = *(const float4*)&Qb[(size_t)(qt * 64 + c) * H_DIM + h];
        QP[(h + 0) * 68 + c] = q.x; QP[(h + 1) * 68 + c] = q.y;
        QP[(h + 2) * 68 + c] = q.z; QP[(h + 3) * 68 + c] = q.w;
        *(float4*)&Vs[c * 68 + h] = *(const float4*)&Vb[(size_t)(kt * 64 + c) * H_DIM + h];
    }
    float4 zv4 = *(const float4*)&Zbuf[(size_t)b * T_DIM + kt * 64 + j * 4];
    float zinv[4] = {1.f / zv4.x, 1.f / zv4.y, 1.f / zv4.z, 1.f / zv4.w};
    __syncthreads();

    // S = Q K^T
    float s[4][4];
#pragma unroll
    for (int u = 0; u < 4; u++)
#pragma unroll
        for (int w = 0; w < 4; w++) s[u][w] = 0.f;
#pragma unroll 4
    for (int h = 0; h < 64; h++) {
        float4 qv = *(const float4*)&QP[h * 68 + i * 4];
        float4 kv = *(const float4*)&Kst[h * 68 + j * 4];
        float qa[4] = {qv.x, qv.y, qv.z, qv.w};
        float ka[4] = {kv.x, kv.y, kv.z, kv.w};
#pragma unroll
        for (int u = 0; u < 4; u++)
#pragma unroll
            for (int w = 0; w < 4; w++) s[u][w] += qa[u] * ka[w];
    }
    __syncthreads();  // done reading Qst; QP becomes Ps

    const bool diag = (qt == kt);
#pragma unroll
    for (int u = 0; u < 4; u++) {
        float pa[4];
#pragma unroll
        for (int w = 0; w < 4; w++) {
            bool ok = !diag || (i * 4 + u >= j * 4 + w);
            pa[w] = ok ? __expf(s[u][w] * SCALE) * zinv[w] : 0.f;
        }
        float4 p; p.x = pa[0]; p.y = pa[1]; p.z = pa[2]; p.w = pa[3];
        *(float4*)&QP[(i * 4 + u) * 68 + j * 4] = p;
    }
    __syncthreads();

    // O += P V
    float o[4][4];
#pragma unroll
    for (int u = 0; u < 4; u++)
#pragma unroll
        for (int w = 0; w < 4; w++) o[u][w] = 0.f;
#pragma unroll 4
    for (int kk = 0; kk < 64; kk++) {
        float4 vv = *(const float4*)&Vs[kk * 68 + j * 4];
#pragma unroll
        for (int u = 0; u < 4; u++) {
            float p = QP[(i * 4 + u) * 68 + kk];
            o[u][0] += p * vv.x;
            o[u][1] += p * vv.y;
            o[u][2] += p * vv.z;
            o[u][3] += p * vv.w;
        }
    }

#pragma unroll
    for (int u = 0; u < 4; u++) {
        float* dst = &out[(size_t)(b * T_DIM + qt * 64 + i * 4 + u) * H_DIM + j * 4];
#pragma unroll
        for (int w = 0; w < 4; w++) atomic_add_f32(dst + w, o[u][w]);
    }
}

// ---------------------------------------------------------------------------
extern "C" void kernel_launch(void* const* d_in, const int* in_sizes, int n_in,
                              void* d_out, int out_size, void* d_ws, size_t ws_size,
                              hipStream_t stream) {
    const float* x  = (const float*)d_in[0];
    const float* Wk = (const float*)d_in[1];
    const float* Wq = (const float*)d_in[2];
    const float* Wv = (const float*)d_in[3];
    float* out = (float*)d_out;

    float* ws = (float*)d_ws;
    const size_t NTH = (size_t)B_DIM * T_DIM * H_DIM;  // 1,048,576
    float* qbuf = ws;
    float* kbuf = ws + NTH;
    float* vbuf = ws + 2 * NTH;
    float* Zbuf = ws + 3 * NTH;

    zero_kernel<<<1040, 256, 0, stream>>>((float4*)out, (float4*)Zbuf);
    proj_kernel<<<dim3((B_DIM * T_DIM) / 128, 3), 256, 0, stream>>>(
        x, Wq, Wk, Wv, qbuf, kbuf, vbuf);
    stats_kernel<<<dim3(NPAIR, B_DIM), 256, 0, stream>>>(qbuf, kbuf, Zbuf);
    out_kernel<<<dim3(NPAIR, B_DIM), 256, 0, stream>>>(qbuf, kbuf, vbuf, Zbuf, out);
}

// Round 3
// 173.536 us; speedup vs baseline: 2.7226x; 2.7226x over previous
//
#include <hip/hip_runtime.h>
#include <hip/hip_bf16.h>
#include <math.h>

#define B_DIM 8
#define T_DIM 2048
#define D_DIM 1024
#define H_DIM 64
#define SCALE 0.125f
#define NT64 (T_DIM / 64)            // 32 tiles of 64 (stats)
#define NPAIR (NT64 * (NT64 + 1) / 2) // 528

typedef __attribute__((ext_vector_type(8))) short bf16x8;
typedef __attribute__((ext_vector_type(4))) float f32x4;

__device__ __forceinline__ f32x4 mfma16(bf16x8 a, bf16x8 b, f32x4 c) {
    return __builtin_amdgcn_mfma_f32_16x16x32_bf16(a, b, c, 0, 0, 0);
}

__device__ __forceinline__ float rcp_fast(float x) {
    float r;
    asm volatile("v_rcp_f32 %0, %1" : "=v"(r) : "v"(x));
    return r;
}

__device__ __forceinline__ short f2bf(float f) {
    __hip_bfloat16 h = __float2bfloat16(f);
    return *reinterpret_cast<short*>(&h);
}

__device__ __forceinline__ void cvt4(float4 v, short* dst) {
    __hip_bfloat162 p0 = __float22bfloat162_rn(make_float2(v.x, v.y));
    __hip_bfloat162 p1 = __float22bfloat162_rn(make_float2(v.z, v.w));
    uint2 u;
    u.x = *reinterpret_cast<unsigned int*>(&p0);
    u.y = *reinterpret_cast<unsigned int*>(&p1);
    *reinterpret_cast<uint2*>(dst) = u;  // dst 8B-aligned
}

// p = qt*(qt+1)/2 + kt, kt <= qt
__device__ __forceinline__ void decode_pair(int p, int& qt, int& kt) {
    float f = sqrtf(8.0f * (float)p + 1.0f);
    int q = (int)((f - 1.0f) * 0.5f);
    while ((q + 1) * (q + 2) / 2 <= p) q++;
    while (q * (q + 1) / 2 > p) q--;
    qt = q;
    kt = p - q * (q + 1) / 2;
}

// ---------------------------------------------------------------------------
// prep: blocks 0..47 transpose-convert W (fp32 [k][h]) -> wt bf16 [m][h][k];
//       blocks 48..63 zero Zbuf (16384 f32).
// ---------------------------------------------------------------------------
__global__ __launch_bounds__(256) void prep_kernel(
    const float* __restrict__ Wq, const float* __restrict__ Wk,
    const float* __restrict__ Wv,
    short* __restrict__ wt, float* __restrict__ Zbuf)
{
    const int blk = blockIdx.x;
    const int tid = threadIdx.x;
    if (blk < 48) {
        const int m = blk >> 4;
        const int ks = (blk & 15) << 6;
        const float* W = (m == 0) ? Wq : (m == 1) ? Wk : Wv;
        __shared__ float tile[64][68];
#pragma unroll
        for (int t = 0; t < 4; t++) {
            int fi = tid + t * 256;
            int k = fi >> 4, h4 = (fi & 15) << 2;
            *(float4*)&tile[k][h4] = *(const float4*)&W[(size_t)(ks + k) * H_DIM + h4];
        }
        __syncthreads();
        const int h = tid >> 2, seg = (tid & 3) << 4;
        __align__(16) short tmp[16];
#pragma unroll
        for (int kk = 0; kk < 16; kk++) tmp[kk] = f2bf(tile[seg + kk][h]);
        short* dst = wt + ((size_t)m * H_DIM + h) * D_DIM + ks + seg;
        *(bf16x8*)dst = *(bf16x8*)tmp;
        *(bf16x8*)(dst + 8) = *(bf16x8*)(tmp + 8);
    } else {
        int idx = (blk - 48) * 256 + tid;  // 4096 float4
        ((float4*)Zbuf)[idx] = make_float4(0.f, 0.f, 0.f, 0.f);
    }
}

// ---------------------------------------------------------------------------
// proj: grid 512 (32 rows each), block 256. Computes q|k|v (192 cols) per
// x-row-tile so x is fetched once. bf16 MFMA 16x16x32, fp32 acc.
// Outputs: qb,kb bf16 row-major [t][h]; vt bf16 transposed [b][h][t].
// ---------------------------------------------------------------------------
__global__ __launch_bounds__(256) void proj_kernel(
    const float* __restrict__ x, const short* __restrict__ wt,
    short* __restrict__ qb, short* __restrict__ kb, short* __restrict__ vt)
{
    __shared__ short xs[32][72];    // A tile [m][k], pitch 144B (16B-mult)
    __shared__ short wsb[192][72];  // B tile [h][k]
    __shared__ short ot[32][200];   // epilogue [row][col], pitch 400B (16B-mult)

    const int tid = threadIdx.x;
    const int wv = tid >> 6;
    const int lane = tid & 63;
    const int l15 = lane & 15;
    const int quad = lane >> 4;
    const int t0 = blockIdx.x * 32;
    const int r0 = (wv & 1) * 16;    // wave row strip
    const int c0 = (wv >> 1) * 96;   // wave col half

    f32x4 acc[6];
#pragma unroll
    for (int c = 0; c < 6; c++) acc[c] = (f32x4){0.f, 0.f, 0.f, 0.f};

    for (int k0 = 0; k0 < D_DIM; k0 += 64) {
        __syncthreads();
#pragma unroll
        for (int t = 0; t < 2; t++) {           // x: 32x64 fp32 -> bf16
            int fi = tid + t * 256;
            int r = fi >> 4, c4 = (fi & 15) << 2;
            float4 v = *(const float4*)&x[(size_t)(t0 + r) * D_DIM + k0 + c4];
            cvt4(v, &xs[r][c4]);
        }
#pragma unroll
        for (int t = 0; t < 6; t++) {           // wt: 192x64 bf16
            int fi = tid + t * 256;
            int hh = fi >> 3, seg = (fi & 7) << 3;
            *(bf16x8*)&wsb[hh][seg] = *(const bf16x8*)&wt[(size_t)hh * D_DIM + k0 + seg];
        }
        __syncthreads();
#pragma unroll
        for (int ks = 0; ks < 2; ks++) {
            bf16x8 xa = *(const bf16x8*)&xs[r0 + l15][ks * 32 + quad * 8];
#pragma unroll
            for (int ct = 0; ct < 6; ct++) {
                bf16x8 wb = *(const bf16x8*)&wsb[c0 + ct * 16 + l15][ks * 32 + quad * 8];
                acc[ct] = mfma16(xa, wb, acc[ct]);
            }
        }
    }
    __syncthreads();
    // C-frags (col=l15, row=quad*4+reg) -> LDS bf16 tile
#pragma unroll
    for (int ct = 0; ct < 6; ct++)
#pragma unroll
        for (int r = 0; r < 4; r++)
            ot[r0 + quad * 4 + r][c0 + ct * 16 + l15] = f2bf(acc[ct][r]);
    __syncthreads();
    // q,k row-major: 512 b128 jobs
#pragma unroll
    for (int t = 0; t < 2; t++) {
        int fi = tid + t * 256;
        int row = fi >> 4, seg = fi & 15;
        bf16x8 v = *(const bf16x8*)&ot[row][seg * 8];
        short* dst = (seg < 8)
            ? &qb[(size_t)(t0 + row) * H_DIM + seg * 8]
            : &kb[(size_t)(t0 + row) * H_DIM + (seg - 8) * 8];
        *(bf16x8*)dst = v;
    }
    // v transposed: vt[b][h][t]
    {
        const int h = tid >> 2, ts = (tid & 3) << 3;
        const int bb = t0 >> 11;
        const int tloc = (t0 & 2047) + ts;
        __align__(16) short tmp[8];
#pragma unroll
        for (int i = 0; i < 8; i++) tmp[i] = ot[ts + i][128 + h];
        *(bf16x8*)&vt[((size_t)bb * H_DIM + h) * T_DIM + tloc] = *(bf16x8*)tmp;
    }
}

// ---------------------------------------------------------------------------
// stats: Z[k] = sum_{q>=k} exp(s*scale). grid (528, 8), 64x64 causal tile
// pairs; S via MFMA; shuffle+LDS reduce; one global atomic per column.
// ---------------------------------------------------------------------------
__global__ __launch_bounds__(256) void stats_kernel(
    const short* __restrict__ qb, const short* __restrict__ kb,
    float* __restrict__ Zbuf)
{
    __shared__ float zred[64];
    const int tid = threadIdx.x;
    const int wv = tid >> 6;
    const int lane = tid & 63;
    const int l15 = lane & 15;
    const int quad = lane >> 4;
    const int b = blockIdx.y;
    int qt, kt;
    decode_pair(blockIdx.x, qt, kt);

    if (tid < 64) zred[tid] = 0.f;
    __syncthreads();

    const short* qB = qb + (size_t)b * T_DIM * H_DIM;
    const short* kB = kb + (size_t)b * T_DIM * H_DIM;
    const int q0 = qt * 64 + wv * 16;
    const bool diag = (qt == kt);

    bf16x8 qa0 = *(const bf16x8*)&qB[(q0 + l15) * H_DIM + quad * 8];
    bf16x8 qa1 = *(const bf16x8*)&qB[(q0 + l15) * H_DIM + 32 + quad * 8];

#pragma unroll
    for (int nt = 0; nt < 4; nt++) {
        const short* kp = &kB[(kt * 64 + nt * 16 + l15) * H_DIM + quad * 8];
        bf16x8 kb0 = *(const bf16x8*)kp;
        bf16x8 kb1 = *(const bf16x8*)(kp + 32);
        f32x4 s = mfma16(qa0, kb0, (f32x4){0.f, 0.f, 0.f, 0.f});
        s = mfma16(qa1, kb1, s);
        float cs = 0.f;
        const int kg = kt * 64 + nt * 16 + l15;
#pragma unroll
        for (int r = 0; r < 4; r++) {
            int qg = q0 + quad * 4 + r;
            float e = __expf(s[r] * SCALE);
            if (diag && kg > qg) e = 0.f;
            cs += e;
        }
        cs += __shfl_xor(cs, 16);
        cs += __shfl_xor(cs, 32);
        if (lane < 16) atomicAdd(&zred[nt * 16 + lane], cs);
    }
    __syncthreads();
    if (tid < 64) unsafeAtomicAdd(&Zbuf[(size_t)b * T_DIM + kt * 64 + tid], zred[tid]);
}

// ---------------------------------------------------------------------------
// out: grid (64, 8), block 256. Block = strip pair {s, 127-s} (16 q-rows
// each, constant total k-length 65 tiles); each wave takes a quarter of each
// strip's k-range -> uniform work, barrier-free main loops. Partial O
// combined in LDS, plain coalesced stores.
// ---------------------------------------------------------------------------
__global__ __launch_bounds__(256) void out_kernel(
    const short* __restrict__ qb, const short* __restrict__ kb,
    const short* __restrict__ vt, const float* __restrict__ Zbuf,
    float* __restrict__ out)
{
    __shared__ float osum[4][2][16][68];   // 34.8 KB
    __shared__ short pbuf[4][16][40];      // per-wave P tile, pitch 80B

    const int tid = threadIdx.x;
    const int wv = tid >> 6;
    const int lane = tid & 63;
    const int l15 = lane & 15;
    const int quad = lane >> 4;
    const int b = blockIdx.y;
    const int sA = blockIdx.x;

    const short* qB = qb + (size_t)b * T_DIM * H_DIM;
    const short* kB = kb + (size_t)b * T_DIM * H_DIM;
    const short* vB = vt + (size_t)b * H_DIM * T_DIM;
    const float* zB = Zbuf + (size_t)b * T_DIM;
    short* pb = &pbuf[wv][0][0];

#pragma unroll
    for (int half = 0; half < 2; half++) {
        const int s = half ? (127 - sA) : sA;
        const int q0 = s * 16;
        const int Ts = (s >> 1) + 1;             // 32-col k-tiles in causal range
        const int lo = (wv * Ts) >> 2;
        const int hi = ((wv + 1) * Ts) >> 2;

        bf16x8 qa0 = *(const bf16x8*)&qB[(q0 + l15) * H_DIM + quad * 8];
        bf16x8 qa1 = *(const bf16x8*)&qB[(q0 + l15) * H_DIM + 32 + quad * 8];

        f32x4 o0 = {0.f,0.f,0.f,0.f}, o1 = {0.f,0.f,0.f,0.f};
        f32x4 o2 = {0.f,0.f,0.f,0.f}, o3 = {0.f,0.f,0.f,0.f};

        for (int kt = lo; kt < hi; kt++) {
            const short* kp = &kB[(kt * 32 + l15) * H_DIM + quad * 8];
            bf16x8 kb00 = *(const bf16x8*)kp;
            bf16x8 kb01 = *(const bf16x8*)(kp + 32);
            bf16x8 kb10 = *(const bf16x8*)(kp + 16 * H_DIM);
            bf16x8 kb11 = *(const bf16x8*)(kp + 16 * H_DIM + 32);

            f32x4 z4 = {0.f,0.f,0.f,0.f};
            f32x4 s0 = mfma16(qa0, kb00, z4);
            s0 = mfma16(qa1, kb01, s0);
            f32x4 s1 = mfma16(qa0, kb10, z4);
            s1 = mfma16(qa1, kb11, s1);

            const float zi0 = rcp_fast(zB[kt * 32 + l15]);
            const float zi1 = rcp_fast(zB[kt * 32 + 16 + l15]);

            const bool fullT = (kt * 32 + 31) <= q0;
            const int kg0 = kt * 32 + l15;
            const int kg1 = kg0 + 16;
#pragma unroll
            for (int r = 0; r < 4; r++) {
                int qg = q0 + quad * 4 + r;
                float e0 = __expf(s0[r] * SCALE) * zi0;
                float e1 = __expf(s1[r] * SCALE) * zi1;
                if (!fullT) {
                    if (kg0 > qg) e0 = 0.f;
                    if (kg1 > qg) e1 = 0.f;
                }
                pb[(quad * 4 + r) * 40 + l15] = f2bf(e0);
                pb[(quad * 4 + r) * 40 + 16 + l15] = f2bf(e1);
            }
            __asm__ volatile("s_waitcnt lgkmcnt(0)" ::: "memory");
            bf16x8 pa = *(const bf16x8*)&pb[l15 * 40 + quad * 8];

            const short* vp = &vB[(size_t)l15 * T_DIM + kt * 32 + quad * 8];
            o0 = mfma16(pa, *(const bf16x8*)vp, o0);
            o1 = mfma16(pa, *(const bf16x8*)(vp + 16 * T_DIM), o1);
            o2 = mfma16(pa, *(const bf16x8*)(vp + 32 * T_DIM), o2);
            o3 = mfma16(pa, *(const bf16x8*)(vp + 48 * T_DIM), o3);
        }
#pragma unroll
        for (int r = 0; r < 4; r++) {
            osum[wv][half][quad * 4 + r][l15]      = o0[r];
            osum[wv][half][quad * 4 + r][16 + l15] = o1[r];
            osum[wv][half][quad * 4 + r][32 + l15] = o2[r];
            osum[wv][half][quad * 4 + r][48 + l15] = o3[r];
        }
    }
    __syncthreads();

    // combine 4 k-quarters, store: 2 strips x 16 rows x 64 h
    const int half = tid >> 7;
    const int row = (tid >> 3) & 15;
    const int h0 = (tid & 7) * 8;
    const int s = half ? (127 - sA) : sA;
    float a[8];
#pragma unroll
    for (int i = 0; i < 8; i++) a[i] = 0.f;
#pragma unroll
    for (int w = 0; w < 4; w++)
#pragma unroll
        for (int i = 0; i < 8; i++) a[i] += osum[w][half][row][h0 + i];
    float* dst = &out[(size_t)(b * T_DIM + s * 16 + row) * H_DIM + h0];
    *(float4*)dst = make_float4(a[0], a[1], a[2], a[3]);
    *(float4*)(dst + 4) = make_float4(a[4], a[5], a[6], a[7]);
}

// ---------------------------------------------------------------------------
extern "C" void kernel_launch(void* const* d_in, const int* in_sizes, int n_in,
                              void* d_out, int out_size, void* d_ws, size_t ws_size,
                              hipStream_t stream) {
    const float* x  = (const float*)d_in[0];
    const float* Wk = (const float*)d_in[1];
    const float* Wq = (const float*)d_in[2];
    const float* Wv = (const float*)d_in[3];
    float* out = (float*)d_out;

    short* qbuf = (short*)d_ws;                       // 16384*64 bf16
    short* kbuf = qbuf + (size_t)16384 * 64;
    short* vtbuf = kbuf + (size_t)16384 * 64;         // [b][h][t]
    short* wtbuf = vtbuf + (size_t)16384 * 64;        // [3][64][1024]
    float* Zbuf = (float*)(wtbuf + (size_t)3 * 64 * 1024);  // [b][t]

    prep_kernel<<<64, 256, 0, stream>>>(Wq, Wk, Wv, wtbuf, Zbuf);
    proj_kernel<<<512, 256, 0, stream>>>(x, wtbuf, qbuf, kbuf, vtbuf);
    stats_kernel<<<dim3(NPAIR, B_DIM), 256, 0, stream>>>(qbuf, kbuf, Zbuf);
    out_kernel<<<dim3(64, B_DIM), 256, 0, stream>>>(qbuf, kbuf, vtbuf, Zbuf, out);
}

// Round 4
// 166.152 us; speedup vs baseline: 2.8436x; 1.0444x over previous
//
#include <hip/hip_runtime.h>
#include <hip/hip_bf16.h>
#include <math.h>

#define B_DIM 8
#define T_DIM 2048
#define D_DIM 1024
#define H_DIM 64
#define SCALE 0.125f

typedef __attribute__((ext_vector_type(8))) short bf16x8;
typedef __attribute__((ext_vector_type(4))) float f32x4;

__device__ __forceinline__ f32x4 mfma16(bf16x8 a, bf16x8 b, f32x4 c) {
    return __builtin_amdgcn_mfma_f32_16x16x32_bf16(a, b, c, 0, 0, 0);
}

__device__ __forceinline__ float rcp_fast(float x) {
    float r;
    asm volatile("v_rcp_f32 %0, %1" : "=v"(r) : "v"(x));
    return r;
}

__device__ __forceinline__ short f2bf(float f) {
    __hip_bfloat16 h = __float2bfloat16(f);
    return *reinterpret_cast<short*>(&h);
}

__device__ __forceinline__ void cvt4(float4 v, short* dst) {
    __hip_bfloat162 p0 = __float22bfloat162_rn(make_float2(v.x, v.y));
    __hip_bfloat162 p1 = __float22bfloat162_rn(make_float2(v.z, v.w));
    uint2 u;
    u.x = *reinterpret_cast<unsigned int*>(&p0);
    u.y = *reinterpret_cast<unsigned int*>(&p1);
    *reinterpret_cast<uint2*>(dst) = u;  // dst 8B-aligned
}

// ---------------------------------------------------------------------------
// prep: transpose-convert W (fp32 [k][h]) -> wt bf16 [m][h][k]. 48 blocks.
// ---------------------------------------------------------------------------
__global__ __launch_bounds__(256) void prep_kernel(
    const float* __restrict__ Wq, const float* __restrict__ Wk,
    const float* __restrict__ Wv, short* __restrict__ wt)
{
    const int blk = blockIdx.x;
    const int tid = threadIdx.x;
    const int m = blk >> 4;
    const int ks = (blk & 15) << 6;
    const float* W = (m == 0) ? Wq : (m == 1) ? Wk : Wv;
    __shared__ float tile[64][68];
#pragma unroll
    for (int t = 0; t < 4; t++) {
        int fi = tid + t * 256;
        int k = fi >> 4, h4 = (fi & 15) << 2;
        *(float4*)&tile[k][h4] = *(const float4*)&W[(size_t)(ks + k) * H_DIM + h4];
    }
    __syncthreads();
    const int h = tid >> 2, seg = (tid & 3) << 4;
    __align__(16) short tmp[16];
#pragma unroll
    for (int kk = 0; kk < 16; kk++) tmp[kk] = f2bf(tile[seg + kk][h]);
    short* dst = wt + ((size_t)m * H_DIM + h) * D_DIM + ks + seg;
    *(bf16x8*)dst = *(bf16x8*)tmp;
    *(bf16x8*)(dst + 8) = *(bf16x8*)(tmp + 8);
}

// ---------------------------------------------------------------------------
// proj: grid 512 (32 rows each), block 256. q|k|v (192 cols) per row tile,
// double-buffered LDS (1 barrier/iter) + global->reg prefetch.
// Outputs: qb,kb bf16 [t][h]; vt bf16 [b][h][t].
// ---------------------------------------------------------------------------
__global__ __launch_bounds__(256) void proj_kernel(
    const float* __restrict__ x, const short* __restrict__ wt,
    short* __restrict__ qb, short* __restrict__ kb, short* __restrict__ vt)
{
    __shared__ short xs[2][32][72];
    __shared__ short wsb[2][192][72];
    __shared__ short ot[32][200];

    const int tid = threadIdx.x;
    const int wv = tid >> 6;
    const int lane = tid & 63;
    const int l15 = lane & 15;
    const int quad = lane >> 4;
    const int t0 = blockIdx.x * 32;
    const int r0 = (wv & 1) * 16;
    const int c0 = (wv >> 1) * 96;

    f32x4 acc[6];
#pragma unroll
    for (int c = 0; c < 6; c++) acc[c] = (f32x4){0.f, 0.f, 0.f, 0.f};

    float4 xr[2];
    bf16x8 wr[6];
    auto load_tile = [&](int k0) {
#pragma unroll
        for (int t = 0; t < 2; t++) {
            int fi = tid + t * 256;
            int r = fi >> 4, c4 = (fi & 15) << 2;
            xr[t] = *(const float4*)&x[(size_t)(t0 + r) * D_DIM + k0 + c4];
        }
#pragma unroll
        for (int t = 0; t < 6; t++) {
            int fi = tid + t * 256;
            int hh = fi >> 3, sg = (fi & 7) << 3;
            wr[t] = *(const bf16x8*)&wt[(size_t)hh * D_DIM + k0 + sg];
        }
    };
    auto store_tile = [&](int buf) {
#pragma unroll
        for (int t = 0; t < 2; t++) {
            int fi = tid + t * 256;
            int r = fi >> 4, c4 = (fi & 15) << 2;
            cvt4(xr[t], &xs[buf][r][c4]);
        }
#pragma unroll
        for (int t = 0; t < 6; t++) {
            int fi = tid + t * 256;
            int hh = fi >> 3, sg = (fi & 7) << 3;
            *(bf16x8*)&wsb[buf][hh][sg] = wr[t];
        }
    };

    load_tile(0);
    store_tile(0);
    __syncthreads();

    for (int it = 0; it < 16; ++it) {
        const int cur = it & 1;
        if (it < 15) load_tile((it + 1) * 64);
#pragma unroll
        for (int ks = 0; ks < 2; ks++) {
            bf16x8 xa = *(const bf16x8*)&xs[cur][r0 + l15][ks * 32 + quad * 8];
#pragma unroll
            for (int ct = 0; ct < 6; ct++) {
                bf16x8 wb = *(const bf16x8*)&wsb[cur][c0 + ct * 16 + l15][ks * 32 + quad * 8];
                acc[ct] = mfma16(xa, wb, acc[ct]);
            }
        }
        if (it < 15) store_tile(cur ^ 1);
        __syncthreads();
    }

    // epilogue: C-frags -> LDS bf16 tile
#pragma unroll
    for (int ct = 0; ct < 6; ct++)
#pragma unroll
        for (int r = 0; r < 4; r++)
            ot[r0 + quad * 4 + r][c0 + ct * 16 + l15] = f2bf(acc[ct][r]);
    __syncthreads();
#pragma unroll
    for (int t = 0; t < 2; t++) {
        int fi = tid + t * 256;
        int row = fi >> 4, sg = fi & 15;
        bf16x8 v = *(const bf16x8*)&ot[row][sg * 8];
        short* dst = (sg < 8)
            ? &qb[(size_t)(t0 + row) * H_DIM + sg * 8]
            : &kb[(size_t)(t0 + row) * H_DIM + (sg - 8) * 8];
        *(bf16x8*)dst = v;
    }
    {
        const int h = tid >> 2, ts = (tid & 3) << 3;
        const int bb = t0 >> 11;
        const int tloc = (t0 & 2047) + ts;
        __align__(16) short tmp[8];
#pragma unroll
        for (int i = 0; i < 8; i++) tmp[i] = ot[ts + i][128 + h];
        *(bf16x8*)&vt[((size_t)bb * H_DIM + h) * T_DIM + tloc] = *(bf16x8*)tmp;
    }
}

// ---------------------------------------------------------------------------
// stats: Z[k] = sum_{q>=k} exp(s*scale). grid (64, 8): block = k-strip pair
// {sa, 127-sa} (16 cols each, 129 q-tiles combined), 4 waves split q-range.
// K stationary in regs, Q streamed w/ ping-pong prefetch. S^T = K*Q^T via
// MFMA. Shuffle+LDS reduce; ONE plain store per column (no atomics/init).
// ---------------------------------------------------------------------------
__global__ __launch_bounds__(256) void stats_kernel(
    const short* __restrict__ qb, const short* __restrict__ kb,
    float* __restrict__ Zbuf)
{
    __shared__ float zred[4][2][16];
    const int tid = threadIdx.x;
    const int wv = tid >> 6;
    const int lane = tid & 63;
    const int l15 = lane & 15;
    const int quad = lane >> 4;
    const int b = blockIdx.y;
    const int sa = blockIdx.x;       // 0..63
    const int sb = 127 - sa;
    const int Ta = 128 - sa;         // q-tiles in strip a (tiles sa..127)

    const short* qB_ = qb + (size_t)b * T_DIM * H_DIM;
    const short* kB_ = kb + (size_t)b * T_DIM * H_DIM;

    bf16x8 ka[2][2];
    {
        const short* kp = &kB_[(sa * 16 + l15) * H_DIM + quad * 8];
        ka[0][0] = *(const bf16x8*)kp;
        ka[0][1] = *(const bf16x8*)(kp + 32);
        const short* kp2 = &kB_[(sb * 16 + l15) * H_DIM + quad * 8];
        ka[1][0] = *(const bf16x8*)kp2;
        ka[1][1] = *(const bf16x8*)(kp2 + 32);
    }

    float acc[2][4];
#pragma unroll
    for (int s = 0; s < 2; s++)
#pragma unroll
        for (int r = 0; r < 4; r++) acc[s][r] = 0.f;

    const int v0 = (wv * 129) >> 2;
    const int v1 = ((wv + 1) * 129) >> 2;

#pragma unroll
    for (int seg = 0; seg < 2; ++seg) {
        const int strip = seg ? sb : sa;
        const int base = seg ? Ta : 0;
        const int lo = seg ? max(v0, Ta) : v0;
        const int hi = seg ? v1 : min(v1, Ta);
        const bf16x8 a0 = ka[seg][0], a1 = ka[seg][1];

        bf16x8 qA0, qA1, qB0, qB1;
        auto loadQ = [&](int v, bf16x8& r0, bf16x8& r1) {
            int qt = strip + (v - base);
            const short* qp = &qB_[(qt * 16 + l15) * H_DIM + quad * 8];
            r0 = *(const bf16x8*)qp;
            r1 = *(const bf16x8*)(qp + 32);
        };
        auto comp = [&](int v, bf16x8 b0, bf16x8 b1) {
            int qt = strip + (v - base);
            f32x4 s = mfma16(a0, b0, (f32x4){0.f, 0.f, 0.f, 0.f});
            s = mfma16(a1, b1, s);
            const bool diag = (qt == strip);
#pragma unroll
            for (int r = 0; r < 4; ++r) {
                float e = __expf(s[r] * SCALE);
                if (diag && (quad * 4 + r) > l15) e = 0.f;
                acc[seg][r] += e;
            }
        };

        int v = lo;
        if (v < hi) loadQ(v, qA0, qA1);
        while (v < hi) {
            if (v + 1 < hi) loadQ(v + 1, qB0, qB1);
            comp(v, qA0, qA1);
            ++v;
            if (v >= hi) break;
            if (v + 1 < hi) loadQ(v + 1, qA0, qA1);
            comp(v, qB0, qB1);
            ++v;
        }
    }

    // butterfly over l15 (sum across 16 q-cols), then LDS combine of 4 waves
#pragma unroll
    for (int seg = 0; seg < 2; ++seg)
#pragma unroll
        for (int r = 0; r < 4; ++r) {
            float z = acc[seg][r];
            z += __shfl_xor(z, 1);
            z += __shfl_xor(z, 2);
            z += __shfl_xor(z, 4);
            z += __shfl_xor(z, 8);
            acc[seg][r] = z;
        }
    if (l15 == 0) {
#pragma unroll
        for (int seg = 0; seg < 2; ++seg)
#pragma unroll
            for (int r = 0; r < 4; ++r)
                zred[wv][seg][quad * 4 + r] = acc[seg][r];
    }
    __syncthreads();
    if (tid < 32) {
        int seg = tid >> 4, col = tid & 15;
        float z = zred[0][seg][col] + zred[1][seg][col] +
                  zred[2][seg][col] + zred[3][seg][col];
        int strip = seg ? sb : sa;
        Zbuf[(size_t)b * T_DIM + strip * 16 + col] = z;
    }
}

// ---------------------------------------------------------------------------
// out: grid (64, 8), block 256. Block = strip pair {s, 127-s} (16 q-rows
// each); waves quarter the k-range. Ping-pong register prefetch of K/V/Z.
// Partial O combined in LDS, coalesced stores.
// ---------------------------------------------------------------------------
__global__ __launch_bounds__(256) void out_kernel(
    const short* __restrict__ qb, const short* __restrict__ kb,
    const short* __restrict__ vt, const float* __restrict__ Zbuf,
    float* __restrict__ out)
{
    __shared__ float osum[4][2][16][68];   // 34.8 KB
    __shared__ short pbuf[4][16][40];      // per-wave P tile

    const int tid = threadIdx.x;
    const int wv = tid >> 6;
    const int lane = tid & 63;
    const int l15 = lane & 15;
    const int quad = lane >> 4;
    const int b = blockIdx.y;
    const int sA = blockIdx.x;

    const short* qB_ = qb + (size_t)b * T_DIM * H_DIM;
    const short* kB_ = kb + (size_t)b * T_DIM * H_DIM;
    const short* vB_ = vt + (size_t)b * H_DIM * T_DIM;
    const float* zB_ = Zbuf + (size_t)b * T_DIM;
    short* pb = &pbuf[wv][0][0];

#pragma unroll
    for (int half = 0; half < 2; half++) {
        const int s = half ? (127 - sA) : sA;
        const int q0 = s * 16;
        const int Ts = (s >> 1) + 1;
        const int lo = (wv * Ts) >> 2;
        const int hi = ((wv + 1) * Ts) >> 2;

        const bf16x8 qa0 = *(const bf16x8*)&qB_[(q0 + l15) * H_DIM + quad * 8];
        const bf16x8 qa1 = *(const bf16x8*)&qB_[(q0 + l15) * H_DIM + 32 + quad * 8];

        f32x4 o0 = {0.f,0.f,0.f,0.f}, o1 = {0.f,0.f,0.f,0.f};
        f32x4 o2 = {0.f,0.f,0.f,0.f}, o3 = {0.f,0.f,0.f,0.f};

        bf16x8 krA[4], vrA[4], krB[4], vrB[4];
        float zA[2], zB2[2];

        auto loadT = [&](int kt, bf16x8* kr, bf16x8* vr, float* zz) {
            const short* kp = &kB_[(kt * 32 + l15) * H_DIM + quad * 8];
            kr[0] = *(const bf16x8*)kp;
            kr[1] = *(const bf16x8*)(kp + 32);
            kr[2] = *(const bf16x8*)(kp + 16 * H_DIM);
            kr[3] = *(const bf16x8*)(kp + 16 * H_DIM + 32);
            const short* vp = &vB_[(size_t)l15 * T_DIM + kt * 32 + quad * 8];
            vr[0] = *(const bf16x8*)vp;
            vr[1] = *(const bf16x8*)(vp + 16 * T_DIM);
            vr[2] = *(const bf16x8*)(vp + 32 * T_DIM);
            vr[3] = *(const bf16x8*)(vp + 48 * T_DIM);
            zz[0] = zB_[kt * 32 + l15];
            zz[1] = zB_[kt * 32 + 16 + l15];
        };
        auto compT = [&](int kt, bf16x8* kr, bf16x8* vr, float* zz) {
            f32x4 z4 = {0.f,0.f,0.f,0.f};
            f32x4 s0 = mfma16(qa0, kr[0], z4);
            s0 = mfma16(qa1, kr[1], s0);
            f32x4 s1 = mfma16(qa0, kr[2], z4);
            s1 = mfma16(qa1, kr[3], s1);
            const float zi0 = rcp_fast(zz[0]);
            const float zi1 = rcp_fast(zz[1]);
            const bool fullT = (kt * 32 + 31) <= q0;
            const int kg0 = kt * 32 + l15;
            const int kg1 = kg0 + 16;
#pragma unroll
            for (int r = 0; r < 4; r++) {
                int qg = q0 + quad * 4 + r;
                float e0 = __expf(s0[r] * SCALE) * zi0;
                float e1 = __expf(s1[r] * SCALE) * zi1;
                if (!fullT) {
                    if (kg0 > qg) e0 = 0.f;
                    if (kg1 > qg) e1 = 0.f;
                }
                pb[(quad * 4 + r) * 40 + l15] = f2bf(e0);
                pb[(quad * 4 + r) * 40 + 16 + l15] = f2bf(e1);
            }
            __asm__ volatile("s_waitcnt lgkmcnt(0)" ::: "memory");
            bf16x8 pa = *(const bf16x8*)&pb[l15 * 40 + quad * 8];
            o0 = mfma16(pa, vr[0], o0);
            o1 = mfma16(pa, vr[1], o1);
            o2 = mfma16(pa, vr[2], o2);
            o3 = mfma16(pa, vr[3], o3);
        };

        int kt = lo;
        if (kt < hi) loadT(kt, krA, vrA, zA);
        while (kt < hi) {
            if (kt + 1 < hi) loadT(kt + 1, krB, vrB, zB2);
            compT(kt, krA, vrA, zA);
            ++kt;
            if (kt >= hi) break;
            if (kt + 1 < hi) loadT(kt + 1, krA, vrA, zA);
            compT(kt, krB, vrB, zB2);
            ++kt;
        }

#pragma unroll
        for (int r = 0; r < 4; r++) {
            osum[wv][half][quad * 4 + r][l15]      = o0[r];
            osum[wv][half][quad * 4 + r][16 + l15] = o1[r];
            osum[wv][half][quad * 4 + r][32 + l15] = o2[r];
            osum[wv][half][quad * 4 + r][48 + l15] = o3[r];
        }
    }
    __syncthreads();

    const int half = tid >> 7;
    const int row = (tid >> 3) & 15;
    const int h0 = (tid & 7) * 8;
    const int s = half ? (127 - sA) : sA;
    float a[8];
#pragma unroll
    for (int i = 0; i < 8; i++) a[i] = 0.f;
#pragma unroll
    for (int w = 0; w < 4; w++)
#pragma unroll
        for (int i = 0; i < 8; i++) a[i] += osum[w][half][row][h0 + i];
    float* dst = &out[(size_t)(b * T_DIM + s * 16 + row) * H_DIM + h0];
    *(float4*)dst = make_float4(a[0], a[1], a[2], a[3]);
    *(float4*)(dst + 4) = make_float4(a[4], a[5], a[6], a[7]);
}

// ---------------------------------------------------------------------------
extern "C" void kernel_launch(void* const* d_in, const int* in_sizes, int n_in,
                              void* d_out, int out_size, void* d_ws, size_t ws_size,
                              hipStream_t stream) {
    const float* x  = (const float*)d_in[0];
    const float* Wk = (const float*)d_in[1];
    const float* Wq = (const float*)d_in[2];
    const float* Wv = (const float*)d_in[3];
    float* out = (float*)d_out;

    short* qbuf = (short*)d_ws;                       // 16384*64 bf16
    short* kbuf = qbuf + (size_t)16384 * 64;
    short* vtbuf = kbuf + (size_t)16384 * 64;         // [b][h][t]
    short* wtbuf = vtbuf + (size_t)16384 * 64;        // [3][64][1024]
    float* Zbuf = (float*)(wtbuf + (size_t)3 * 64 * 1024);  // [b][t]

    prep_kernel<<<48, 256, 0, stream>>>(Wq, Wk, Wv, wtbuf);
    proj_kernel<<<512, 256, 0, stream>>>(x, wtbuf, qbuf, kbuf, vtbuf);
    stats_kernel<<<dim3(64, B_DIM), 256, 0, stream>>>(qbuf, kbuf, Zbuf);
    out_kernel<<<dim3(64, B_DIM), 256, 0, stream>>>(qbuf, kbuf, vtbuf, Zbuf, out);
}